// Round 11
// baseline (3891.134 us; speedup 1.0000x reference)
//
#include <hip/hip_runtime.h>
#include <cstdint>
#include <cstddef>

#define HID 64
#define RPG 16          // rows per GROUP = MFMA N-tile (swapped form)
#define NGRP 2          // independent row-groups per block
#define HSTR 72         // ushorts per h row: 144 B (16B-aligned)
#define XSTR 68         // floats per x row: 272 B (16B-aligned)

typedef short bf16x8 __attribute__((ext_vector_type(8)));
typedef float f32x4 __attribute__((ext_vector_type(4)));

// Exact-erf GELU via Abramowitz & Stegun 7.1.26 (max |erf err| ~1.5e-7).
__device__ __forceinline__ float fast_gelu(float z) {
    float u = z * 0.70710678118654752f;
    float a = __builtin_fabsf(u);
    float t = __builtin_amdgcn_rcpf(__builtin_fmaf(0.3275911f, a, 1.0f));
    float s = u * 1.20112240878645f;            // sqrt(log2 e)
    float e = __builtin_amdgcn_exp2f(-(s * s)); // exp(-u^2)
    float p =                   1.061405429f;
    p = __builtin_fmaf(p, t, -1.453152027f);
    p = __builtin_fmaf(p, t,  1.421413741f);
    p = __builtin_fmaf(p, t, -0.284496736f);
    p = __builtin_fmaf(p, t,  0.254829592f);
    p = p * t;
    float er = __builtin_fmaf(-p, e, 1.0f);
    er = __builtin_copysignf(er, u);
    float zh = 0.5f * z;
    return __builtin_fmaf(zh, er, zh);
}

__device__ __forceinline__ ushort bf16_hi(float f) {
    return (ushort)(__float_as_uint(f) >> 16);
}
__device__ __forceinline__ float bf16_f(ushort u) {
    return __uint_as_float(((unsigned)u) << 16);
}

// Pack top halves of two f32 bit-patterns into one u32: {lo16=a>>16, hi16=b>>16}.
#define PKHI(b_, a_) __builtin_amdgcn_perm((b_), (a_), 0x07060302u)

// One step, swapped form: D'[c'][r] = sum_k W^T[c'][k] h[k][r].
// A = W^T (static regs), B = h read [r][k] row-major (4x ds_read_b128).
// C/D: col=lane&15 = r (fixed rr), row = 4q+e = c -> this lane's 4 outputs are
// CONTIGUOUS in c. Bias rides as C-in of the ac1 chain. Wave finishes all 4
// elements; writes hi/lo planes as one ds_write_b64 each. One barrier per step.
#define STEP(RHI, RLO, WHI, WLO, XB) { \
    const bf16x8 Hhi0 = *reinterpret_cast<const bf16x8*>(RHI); \
    const bf16x8 Hhi1 = *reinterpret_cast<const bf16x8*>((RHI) + 32); \
    const bf16x8 Hlo0 = *reinterpret_cast<const bf16x8*>(RLO); \
    const bf16x8 Hlo1 = *reinterpret_cast<const bf16x8*>((RLO) + 32); \
    const f32x4 bi = { __builtin_fmaf((XB), win0, cb0), \
                       __builtin_fmaf((XB), win1, cb1), \
                       __builtin_fmaf((XB), win2, cb2), \
                       __builtin_fmaf((XB), win3, cb3) }; \
    const f32x4 zz = {0.f, 0.f, 0.f, 0.f}; \
    f32x4 ahh = __builtin_amdgcn_mfma_f32_16x16x32_bf16(Whi0, Hhi0, zz, 0, 0, 0); \
    f32x4 ac1 = __builtin_amdgcn_mfma_f32_16x16x32_bf16(Whi0, Hlo0, bi, 0, 0, 0); \
    f32x4 ac2 = __builtin_amdgcn_mfma_f32_16x16x32_bf16(Wlo0, Hhi0, zz, 0, 0, 0); \
    ahh = __builtin_amdgcn_mfma_f32_16x16x32_bf16(Whi1, Hhi1, ahh, 0, 0, 0); \
    ac1 = __builtin_amdgcn_mfma_f32_16x16x32_bf16(Whi1, Hlo1, ac1, 0, 0, 0); \
    ac2 = __builtin_amdgcn_mfma_f32_16x16x32_bf16(Wlo1, Hhi1, ac2, 0, 0, 0); \
    const float z0 = (ahh[0] + ac1[0]) + ac2[0]; \
    const float z1 = (ahh[1] + ac1[1]) + ac2[1]; \
    const float z2 = (ahh[2] + ac1[2]) + ac2[2]; \
    const float z3 = (ahh[3] + ac1[3]) + ac2[3]; \
    const float h0 = fast_gelu(z0); \
    const float h1 = fast_gelu(z1); \
    const float h2 = fast_gelu(z2); \
    const float h3 = fast_gelu(z3); \
    const unsigned hb0 = __float_as_uint(h0), hb1 = __float_as_uint(h1); \
    const unsigned hb2 = __float_as_uint(h2), hb3 = __float_as_uint(h3); \
    uint2 hpk; hpk.x = PKHI(hb1, hb0); hpk.y = PKHI(hb3, hb2); \
    *(WHI) = hpk; \
    const unsigned lb0 = __float_as_uint(h0 - __uint_as_float(hb0 & 0xffff0000u)); \
    const unsigned lb1 = __float_as_uint(h1 - __uint_as_float(hb1 & 0xffff0000u)); \
    const unsigned lb2 = __float_as_uint(h2 - __uint_as_float(hb2 & 0xffff0000u)); \
    const unsigned lb3 = __float_as_uint(h3 - __uint_as_float(hb3 & 0xffff0000u)); \
    uint2 lpk; lpk.x = PKHI(lb1, lb0); lpk.y = PKHI(lb3, lb2); \
    *(WLO) = lpk; \
    __syncthreads(); }

__global__ __launch_bounds__(512, 2)
void ssm_kernel(const float* __restrict__ x,
                const float* __restrict__ W_in,
                const float* __restrict__ b_in,
                const float* __restrict__ W_s,
                const float* __restrict__ b_s,
                const float* __restrict__ W_out,
                const float* __restrict__ b_out,
                float* __restrict__ out,
                int B, int T) {
    // h state per group, split-bf16, ping-pong: hlds[grp][pp][hi/lo][r*HSTR+k]
    __shared__ ushort hlds[NGRP][2][2][RPG * HSTR];
    __shared__ float  xlds[NGRP * RPG][XSTR];      // x[row][t_local], padded

    const int tid  = threadIdx.x;
    const int ww   = tid >> 6;        // wave 0..7
    const int grp  = ww >> 2;         // group 0/1: independent 16-row recurrence
    const int g    = ww & 3;          // c-tile within group: [16g, 16g+16)
    const int lane = tid & 63;
    const int q    = lane >> 4;
    const int rr   = lane & 15;       // lane's row within group (C col-index)
    const int bA   = blockIdx.x * (NGRP * RPG);
    const int cq   = 16 * g + 4 * q;  // c-quad base this lane produces

    if (bA >= B) return;

    // A-operand = W^T tile g (static): lane rr holds W^T[c'=rr][k=8q+e].
    bf16x8 Whi0, Whi1, Wlo0, Wlo1;
    const int wcol = 16 * g + rr;
#pragma unroll
    for (int e = 0; e < 8; ++e) {
        {   const float wf = W_s[(8 * q + e) * HID + wcol];
            const ushort hi = bf16_hi(wf);
            Whi0[e] = (short)hi;
            Wlo0[e] = (short)bf16_hi(wf - bf16_f(hi)); }
        {   const float wf = W_s[(32 + 8 * q + e) * HID + wcol];
            const ushort hi = bf16_hi(wf);
            Whi1[e] = (short)hi;
            Wlo1[e] = (short)bf16_hi(wf - bf16_f(hi)); }
    }
    // Pin in VGPRs (round-1 lesson: const global loads get rematerialized).
    asm volatile("" : "+v"(Whi0), "+v"(Whi1), "+v"(Wlo0), "+v"(Wlo1));

    // Per-element input-projection constants for this lane's c-quad.
    const float win0 = W_in[cq + 0], win1 = W_in[cq + 1];
    const float win2 = W_in[cq + 2], win3 = W_in[cq + 3];
    const float cb0 = b_in[cq + 0] + b_s[cq + 0];
    const float cb1 = b_in[cq + 1] + b_s[cq + 1];
    const float cb2 = b_in[cq + 2] + b_s[cq + 2];
    const float cb3 = b_in[cq + 3] + b_s[cq + 3];

    // zero all h buffers; ordered before first read by the staging barrier
    {
        ushort* p = &hlds[0][0][0][0];
        for (int i = tid; i < NGRP * 2 * 2 * RPG * HSTR; i += 512) p[i] = 0;
    }

    // Loop-invariant LDS pointers (group-local).
    const ushort* const rhiA = &hlds[grp][0][0][rr * HSTR + 8 * q];
    const ushort* const rloA = &hlds[grp][0][1][rr * HSTR + 8 * q];
    const ushort* const rhiB = &hlds[grp][1][0][rr * HSTR + 8 * q];
    const ushort* const rloB = &hlds[grp][1][1][rr * HSTR + 8 * q];
    uint2* const whiA = reinterpret_cast<uint2*>(&hlds[grp][0][0][rr * HSTR + cq]);
    uint2* const wloA = reinterpret_cast<uint2*>(&hlds[grp][0][1][rr * HSTR + cq]);
    uint2* const whiB = reinterpret_cast<uint2*>(&hlds[grp][1][0][rr * HSTR + cq]);
    uint2* const wloB = reinterpret_cast<uint2*>(&hlds[grp][1][1][rr * HSTR + cq]);
    const float* const xrow = &xlds[RPG * grp + rr][0];

    const int nch = T >> 6;           // T multiple of 64 (8192 here)

    for (int tc = 0; tc < nch; ++tc) {
        // Stage x for BOTH groups (32 rows x 64 t): one float4 per thread.
        {
            const int row = tid >> 4;         // 0..31
            const int ch  = tid & 15;         // 0..15 -> 4 floats each
            const float4 xg = *reinterpret_cast<const float4*>(
                &x[(size_t)(bA + row) * (size_t)T + (size_t)(tc * 64 + ch * 4)]);
            *reinterpret_cast<float4*>(&xlds[row][ch * 4]) = xg;
        }
        __syncthreads();

#pragma unroll 1
        for (int t4 = 0; t4 < 16; ++t4) {
            const f32x4 xq = *reinterpret_cast<const f32x4*>(xrow + t4 * 4);
            STEP(rhiA, rloA, whiB, wloB, xq[0])
            STEP(rhiB, rloB, whiA, wloA, xq[1])
            STEP(rhiA, rloA, whiB, wloB, xq[2])
            STEP(rhiB, rloB, whiA, wloA, xq[3])
        }
    }

    // Epilogue: h final in hlds[grp][0] (even step count). One wave per group.
    if ((ww & 3) == 0) {
        const int r  = lane >> 2;
        const int p4 = lane & 3;
        const ushort* hp = &hlds[grp][0][0][r * HSTR + p4 * 16];
        const ushort* lp = &hlds[grp][0][1][r * HSTR + p4 * 16];
        float s = 0.f;
#pragma unroll
        for (int j = 0; j < 16; ++j)
            s = __builtin_fmaf(bf16_f(hp[j]) + bf16_f(lp[j]), W_out[p4 * 16 + j], s);
        s += __shfl_xor(s, 1, 64);
        s += __shfl_xor(s, 2, 64);
        if (p4 == 0) out[bA + RPG * grp + r] = s + b_out[0];
    }
}

extern "C" void kernel_launch(void* const* d_in, const int* in_sizes, int n_in,
                              void* d_out, int out_size, void* d_ws, size_t ws_size,
                              hipStream_t stream) {
    const float* x     = (const float*)d_in[0];
    const float* W_in  = (const float*)d_in[1];
    const float* b_in  = (const float*)d_in[2];
    const float* W_s   = (const float*)d_in[3];
    const float* b_s   = (const float*)d_in[4];
    const float* W_out = (const float*)d_in[5];
    const float* b_out = (const float*)d_in[6];
    float* out = (float*)d_out;

    const int B = out_size;                 // [B,1] output
    const int T = in_sizes[0] / B;          // x is [B,T,1]

    const int rows_per_block = NGRP * RPG;  // 32
    const int blocks = (B + rows_per_block - 1) / rows_per_block;   // 128
    ssm_kernel<<<blocks, 512, 0, stream>>>(
        x, W_in, b_in, W_s, b_s, W_out, b_out, out, B, T);
}

// Round 12
// 3090.318 us; speedup vs baseline: 1.2591x; 1.2591x over previous
//
#include <hip/hip_runtime.h>
#include <cstdint>
#include <cstddef>

#define HID 64
#define RPG 16          // rows per block = MFMA N-tile (swapped form)
#define HSTR 72         // ushorts per h row: 144 B (16B-aligned)
#define XSTR 68         // floats per x row: 272 B (16B-aligned)

typedef short bf16x8 __attribute__((ext_vector_type(8)));
typedef float f32x4 __attribute__((ext_vector_type(4)));

// Exact-erf GELU via Abramowitz & Stegun 7.1.26 (max |erf err| ~1.5e-7).
__device__ __forceinline__ float fast_gelu(float z) {
    float u = z * 0.70710678118654752f;
    float a = __builtin_fabsf(u);
    float t = __builtin_amdgcn_rcpf(__builtin_fmaf(0.3275911f, a, 1.0f));
    float s = u * 1.20112240878645f;            // sqrt(log2 e)
    float e = __builtin_amdgcn_exp2f(-(s * s)); // exp(-u^2)
    float p =                   1.061405429f;
    p = __builtin_fmaf(p, t, -1.453152027f);
    p = __builtin_fmaf(p, t,  1.421413741f);
    p = __builtin_fmaf(p, t, -0.284496736f);
    p = __builtin_fmaf(p, t,  0.254829592f);
    p = p * t;
    float er = __builtin_fmaf(-p, e, 1.0f);
    er = __builtin_copysignf(er, u);
    float zh = 0.5f * z;
    return __builtin_fmaf(zh, er, zh);
}

__device__ __forceinline__ ushort bf16_hi(float f) {
    return (ushort)(__float_as_uint(f) >> 16);
}
__device__ __forceinline__ float bf16_f(ushort u) {
    return __uint_as_float(((unsigned)u) << 16);
}

// Pack top halves of two f32 bit-patterns into one u32: {lo16=a>>16, hi16=b>>16}.
#define PKHI(b_, a_) __builtin_amdgcn_perm((b_), (a_), 0x07060302u)

// One K-split step. Wave (g,hf) covers k in [32hf, 32hf+32): reads ONLY its
// K-half of the hi/lo h planes (2 x b128), runs 3 independent K=32 MFMAs,
// ships the partner's two elements (S0,S1) as float2 via xch, receives its
// own missing partial, finishes elements K0,K1 (gelu + split-bf16) and writes
// them as one packed u32 per plane. Two barriers per step (exchange + h-ready).
#define STEP(RHI, RLO, WHI, WLO, XB, BIASED, K0, K1, S0, S1) { \
    const bf16x8 Hhi = *reinterpret_cast<const bf16x8*>(RHI); \
    const bf16x8 Hlo = *reinterpret_cast<const bf16x8*>(RLO); \
    f32x4 ci; \
    ci[0] = (BIASED) ? __builtin_fmaf((XB), win0, cb0) : 0.f; \
    ci[1] = (BIASED) ? __builtin_fmaf((XB), win1, cb1) : 0.f; \
    ci[2] = (BIASED) ? __builtin_fmaf((XB), win2, cb2) : 0.f; \
    ci[3] = (BIASED) ? __builtin_fmaf((XB), win3, cb3) : 0.f; \
    const f32x4 zz = {0.f, 0.f, 0.f, 0.f}; \
    const f32x4 ahh = __builtin_amdgcn_mfma_f32_16x16x32_bf16(Whi, Hhi, ci, 0, 0, 0); \
    const f32x4 ac1 = __builtin_amdgcn_mfma_f32_16x16x32_bf16(Whi, Hlo, zz, 0, 0, 0); \
    const f32x4 ac2 = __builtin_amdgcn_mfma_f32_16x16x32_bf16(Wlo, Hhi, zz, 0, 0, 0); \
    const f32x4 ps = (ahh + ac1) + ac2; \
    float2 snd; snd.x = ps[S0]; snd.y = ps[S1]; \
    *xw = snd; \
    __syncthreads(); \
    const float2 rc = *xr; \
    const float z0 = ps[K0] + rc.x; \
    const float z1 = ps[K1] + rc.y; \
    const float h0 = fast_gelu(z0); \
    const float h1 = fast_gelu(z1); \
    const unsigned hb0 = __float_as_uint(h0), hb1 = __float_as_uint(h1); \
    *(WHI) = PKHI(hb1, hb0); \
    const unsigned lb0 = __float_as_uint(h0 - __uint_as_float(hb0 & 0xffff0000u)); \
    const unsigned lb1 = __float_as_uint(h1 - __uint_as_float(hb1 & 0xffff0000u)); \
    *(WLO) = PKHI(lb1, lb0); \
    __syncthreads(); }

// Main loop specialized per K-half so element indices are literals.
#define MAINLOOP(BIASED, K0, K1, S0, S1) { \
    for (int tc = 0; tc < nch; ++tc) { \
        { \
            const int row = tid >> 5;        /* 0..15 */ \
            const int ch  = tid & 31;        /* 0..31 -> 2 floats each */ \
            const float2 xg = *reinterpret_cast<const float2*>( \
                &x[(size_t)(bA + row) * (size_t)T + (size_t)(tc * 64 + ch * 2)]); \
            *reinterpret_cast<float2*>(&xlds[row][ch * 2]) = xg; \
        } \
        __syncthreads(); \
        _Pragma("unroll 1") \
        for (int t4 = 0; t4 < 16; ++t4) { \
            const f32x4 xq = *reinterpret_cast<const f32x4*>(&xlds[rr][t4 * 4]); \
            STEP(rhiA, rloA, whiB, wloB, xq[0], BIASED, K0, K1, S0, S1) \
            STEP(rhiB, rloB, whiA, wloA, xq[1], BIASED, K0, K1, S0, S1) \
            STEP(rhiA, rloA, whiB, wloB, xq[2], BIASED, K0, K1, S0, S1) \
            STEP(rhiB, rloB, whiA, wloA, xq[3], BIASED, K0, K1, S0, S1) \
        } \
    } }

__global__ __launch_bounds__(512, 2)
void ssm_kernel(const float* __restrict__ x,
                const float* __restrict__ W_in,
                const float* __restrict__ b_in,
                const float* __restrict__ W_s,
                const float* __restrict__ b_s,
                const float* __restrict__ W_out,
                const float* __restrict__ b_out,
                float* __restrict__ out,
                int B, int T) {
    // h state split-bf16, ping-pong, [r][k] row-major: hlds[pp][hi/lo][r*HSTR+k]
    __shared__ ushort hlds[2][2][RPG * HSTR];
    __shared__ float  xlds[RPG][XSTR];      // x[row][t_local], padded
    __shared__ float  xch[8][64][2];        // partial exchange: [wave][lane][2]

    const int tid  = threadIdx.x;
    const int ww   = tid >> 6;        // wave 0..7
    const int g    = ww & 3;          // c-tile: owns cols [16g, 16g+16)
    const int hf   = ww >> 2;         // K-half 0/1; finishes elements {2hf,2hf+1}
    const int lane = tid & 63;
    const int q    = lane >> 4;
    const int rr   = lane & 15;       // lane's batch row (C col-index)
    const int bA   = blockIdx.x * RPG;
    const int cq   = 16 * g + 4 * q;  // c-quad base this lane produces

    if (bA >= B) return;

    // A-operand = W^T tile g, K-half hf ONLY: lane rr holds W^T[rr][32hf+8q+e].
    bf16x8 Whi, Wlo;
    const int wcol = 16 * g + rr;
#pragma unroll
    for (int e = 0; e < 8; ++e) {
        const float wf = W_s[(32 * hf + 8 * q + e) * HID + wcol];
        const ushort hi = bf16_hi(wf);
        Whi[e] = (short)hi;
        Wlo[e] = (short)bf16_hi(wf - bf16_f(hi));
    }
    // Pin in VGPRs (round-1 lesson: const global loads get rematerialized).
    asm volatile("" : "+v"(Whi), "+v"(Wlo));

    // Per-element input-projection constants for this lane's c-quad.
    const float win0 = W_in[cq + 0], win1 = W_in[cq + 1];
    const float win2 = W_in[cq + 2], win3 = W_in[cq + 3];
    const float cb0 = b_in[cq + 0] + b_s[cq + 0];
    const float cb1 = b_in[cq + 1] + b_s[cq + 1];
    const float cb2 = b_in[cq + 2] + b_s[cq + 2];
    const float cb3 = b_in[cq + 3] + b_s[cq + 3];

    // zero h buffers; ordered before first read by the staging barrier
    {
        ushort* p = &hlds[0][0][0];
        for (int i = tid; i < 2 * 2 * RPG * HSTR; i += 512) p[i] = 0;
    }

    // Loop-invariant LDS pointers. Reads cover this wave's K-half only.
    const ushort* const rhiA = &hlds[0][0][rr * HSTR + 32 * hf + 8 * q];
    const ushort* const rloA = &hlds[0][1][rr * HSTR + 32 * hf + 8 * q];
    const ushort* const rhiB = &hlds[1][0][rr * HSTR + 32 * hf + 8 * q];
    const ushort* const rloB = &hlds[1][1][rr * HSTR + 32 * hf + 8 * q];
    // Writes: this wave owns elements {2hf, 2hf+1} -> one u32 per plane.
    unsigned* const whiA = reinterpret_cast<unsigned*>(&hlds[0][0][rr * HSTR + cq + 2 * hf]);
    unsigned* const wloA = reinterpret_cast<unsigned*>(&hlds[0][1][rr * HSTR + cq + 2 * hf]);
    unsigned* const whiB = reinterpret_cast<unsigned*>(&hlds[1][0][rr * HSTR + cq + 2 * hf]);
    unsigned* const wloB = reinterpret_cast<unsigned*>(&hlds[1][1][rr * HSTR + cq + 2 * hf]);
    // Exchange slots: write own, read K-partner's (ww ^ 4).
    float2* const xw = reinterpret_cast<float2*>(&xch[ww][lane][0]);
    const float2* const xr = reinterpret_cast<const float2*>(&xch[ww ^ 4][lane][0]);

    const int nch = T >> 6;           // T multiple of 64 (8192 here)

    if (hf == 0) { MAINLOOP(1, 0, 1, 2, 3) } else { MAINLOOP(0, 2, 3, 0, 1) }

    // Epilogue: h final in hlds[0] (even step count). out[b] = h.W_out + b_out.
    if (ww == 0) {
        const int r  = lane >> 2;
        const int p4 = lane & 3;
        const ushort* hp = &hlds[0][0][r * HSTR + p4 * 16];
        const ushort* lp = &hlds[0][1][r * HSTR + p4 * 16];
        float s = 0.f;
#pragma unroll
        for (int j = 0; j < 16; ++j)
            s = __builtin_fmaf(bf16_f(hp[j]) + bf16_f(lp[j]), W_out[p4 * 16 + j], s);
        s += __shfl_xor(s, 1, 64);
        s += __shfl_xor(s, 2, 64);
        if (p4 == 0) out[bA + r] = s + b_out[0];
    }
}

extern "C" void kernel_launch(void* const* d_in, const int* in_sizes, int n_in,
                              void* d_out, int out_size, void* d_ws, size_t ws_size,
                              hipStream_t stream) {
    const float* x     = (const float*)d_in[0];
    const float* W_in  = (const float*)d_in[1];
    const float* b_in  = (const float*)d_in[2];
    const float* W_s   = (const float*)d_in[3];
    const float* b_s   = (const float*)d_in[4];
    const float* W_out = (const float*)d_in[5];
    const float* b_out = (const float*)d_in[6];
    float* out = (float*)d_out;

    const int B = out_size;                 // [B,1] output
    const int T = in_sizes[0] / B;          // x is [B,T,1]

    const int blocks = B / RPG;             // 256 for B=4096
    ssm_kernel<<<blocks, 512, 0, stream>>>(
        x, W_in, b_in, W_s, b_s, W_out, b_out, out, B, T);
}

// Round 13
// 2579.662 us; speedup vs baseline: 1.5084x; 1.1980x over previous
//
#include <hip/hip_runtime.h>
#include <cstdint>
#include <cstddef>

#define HID 64
#define RPG 16          // rows per block = MFMA N-tile (swapped form)
#define ROWU 144        // ushorts per h row stripe (288B): [hi 8x16B][lo 8x16B][pad 32B]
#define XSTR 68         // floats per x row: 272 B

typedef short bf16x8 __attribute__((ext_vector_type(8)));
typedef float f32x4 __attribute__((ext_vector_type(4)));

// Exact-erf GELU via Abramowitz & Stegun 7.1.26 (max |erf err| ~1.5e-7).
__device__ __forceinline__ float fast_gelu(float z) {
    float u = z * 0.70710678118654752f;
    float a = __builtin_fabsf(u);
    float t = __builtin_amdgcn_rcpf(__builtin_fmaf(0.3275911f, a, 1.0f));
    float s = u * 1.20112240878645f;            // sqrt(log2 e)
    float e = __builtin_amdgcn_exp2f(-(s * s)); // exp(-u^2)
    float p =                   1.061405429f;
    p = __builtin_fmaf(p, t, -1.453152027f);
    p = __builtin_fmaf(p, t,  1.421413741f);
    p = __builtin_fmaf(p, t, -0.284496736f);
    p = __builtin_fmaf(p, t,  0.254829592f);
    p = p * t;
    float er = __builtin_fmaf(-p, e, 1.0f);
    er = __builtin_copysignf(er, u);
    float zh = 0.5f * z;
    return __builtin_fmaf(zh, er, zh);
}

__device__ __forceinline__ ushort bf16_hi(float f) {
    return (ushort)(__float_as_uint(f) >> 16);
}
__device__ __forceinline__ float bf16_f(ushort u) {
    return __uint_as_float(((unsigned)u) << 16);
}

// Pack top halves of two f32 bit-patterns into one u32: {lo16=a>>16, hi16=b>>16}.
#define PKHI(b_, a_) __builtin_amdgcn_perm((b_), (a_), 0x07060302u)

// One step, swapped form: D'[c'][r] = sum_k W^T[c'][k] h[k][r].
// A = W^T (static regs), B = h from swizzled LDS stripes (4x ds_read_b128:
// hi0, hi1, lo0, lo1 via two addr regs + offset:128 immediates).
// Bias rides as C-in of the ac1 chain at literal elements E0,E1.
// This wave finishes elements E0,E1 and writes one u32 per plane. One barrier.
#define STEP(RA0, RA1, WHI, WLO, XB, E0, E1) { \
    const bf16x8 Hhi0 = *reinterpret_cast<const bf16x8*>(RA0); \
    const bf16x8 Hlo0 = *reinterpret_cast<const bf16x8*>((RA0) + 64); \
    const bf16x8 Hhi1 = *reinterpret_cast<const bf16x8*>(RA1); \
    const bf16x8 Hlo1 = *reinterpret_cast<const bf16x8*>((RA1) + 64); \
    f32x4 ci = {0.f, 0.f, 0.f, 0.f}; \
    ci[E0] = __builtin_fmaf((XB), win0, cb0); \
    ci[E1] = __builtin_fmaf((XB), win1, cb1); \
    const f32x4 zz = {0.f, 0.f, 0.f, 0.f}; \
    f32x4 ahh = __builtin_amdgcn_mfma_f32_16x16x32_bf16(Whi0, Hhi0, zz, 0, 0, 0); \
    f32x4 ac1 = __builtin_amdgcn_mfma_f32_16x16x32_bf16(Whi0, Hlo0, ci, 0, 0, 0); \
    f32x4 ac2 = __builtin_amdgcn_mfma_f32_16x16x32_bf16(Wlo0, Hhi0, zz, 0, 0, 0); \
    ahh = __builtin_amdgcn_mfma_f32_16x16x32_bf16(Whi1, Hhi1, ahh, 0, 0, 0); \
    ac1 = __builtin_amdgcn_mfma_f32_16x16x32_bf16(Whi1, Hlo1, ac1, 0, 0, 0); \
    ac2 = __builtin_amdgcn_mfma_f32_16x16x32_bf16(Wlo1, Hhi1, ac2, 0, 0, 0); \
    const float z0 = (ahh[E0] + ac1[E0]) + ac2[E0]; \
    const float z1 = (ahh[E1] + ac1[E1]) + ac2[E1]; \
    const float h0 = fast_gelu(z0); \
    const float h1 = fast_gelu(z1); \
    const unsigned hb0 = __float_as_uint(h0), hb1 = __float_as_uint(h1); \
    *(WHI) = PKHI(hb1, hb0); \
    const unsigned lb0 = __float_as_uint(h0 - __uint_as_float(hb0 & 0xffff0000u)); \
    const unsigned lb1 = __float_as_uint(h1 - __uint_as_float(hb1 & 0xffff0000u)); \
    *(WLO) = PKHI(lb1, lb0); \
    __syncthreads(); }

// Main loop specialized per element-half so all C-vector indices are literals.
#define MAINLOOP(E0, E1) { \
    const float win0 = W_in[cq + E0]; \
    const float win1 = W_in[cq + E1]; \
    const float cb0  = b_in[cq + E0] + b_s[cq + E0]; \
    const float cb1  = b_in[cq + E1] + b_s[cq + E1]; \
    for (int tc = 0; tc < nch; ++tc) { \
        const size_t tg = (size_t)tc * 64; \
        { \
            const int row = tid >> 5;        /* 0..15 */ \
            const int ch  = tid & 31;        /* 0..31 -> 2 floats each */ \
            const float2 xg = *reinterpret_cast<const float2*>( \
                &x[(size_t)(bA + row) * (size_t)T + tg + ch * 2]); \
            *reinterpret_cast<float2*>(&xlds[row][ch * 2]) = xg; \
        } \
        __syncthreads(); \
        _Pragma("unroll 1") \
        for (int t4 = 0; t4 < 16; ++t4) { \
            const f32x4 xq = *reinterpret_cast<const f32x4*>(&xlds[rr][t4 * 4]); \
            STEP(rA0, rA1, whiB, wloB, xq[0], E0, E1) \
            STEP(rB0, rB1, whiA, wloA, xq[1], E0, E1) \
            STEP(rA0, rA1, whiB, wloB, xq[2], E0, E1) \
            STEP(rB0, rB1, whiA, wloA, xq[3], E0, E1) \
        } \
    } }

__global__ __launch_bounds__(512, 2)
void ssm_kernel(const float* __restrict__ x,
                const float* __restrict__ W_in,
                const float* __restrict__ b_in,
                const float* __restrict__ W_s,
                const float* __restrict__ b_s,
                const float* __restrict__ W_out,
                const float* __restrict__ b_out,
                float* __restrict__ out,
                int B, int T) {
    // h state: per row one 288B stripe = [hi 8 slots][lo 8 slots][pad], XOR-swizzled
    // 16B slots (phys = s ^ (rr&7) ^ 5*(rr>>3)); ping-pong buffers.
    __shared__ ushort hlds[2][RPG * ROWU];
    __shared__ float  xlds[RPG][XSTR];      // x[row][t_local], padded

    const int tid  = threadIdx.x;
    const int ww   = tid >> 6;        // wave 0..7
    const int g    = ww & 3;          // c-tile: owns cols [16g, 16g+16)
    const int hf   = ww >> 2;         // element-half: finishes {2hf, 2hf+1}
    const int lane = tid & 63;
    const int q    = lane >> 4;
    const int rr   = lane & 15;       // lane's batch row (C col-index)
    const int bA   = blockIdx.x * RPG;
    const int cq   = 16 * g + 4 * q;  // c-quad base this lane produces

    if (bA >= B) return;

    // A-operand = W^T tile g (static): lane rr holds W^T[c'=rr][k=8q+e].
    bf16x8 Whi0, Whi1, Wlo0, Wlo1;
    const int wcol = 16 * g + rr;
#pragma unroll
    for (int e = 0; e < 8; ++e) {
        {   const float wf = W_s[(8 * q + e) * HID + wcol];
            const ushort hi = bf16_hi(wf);
            Whi0[e] = (short)hi;
            Wlo0[e] = (short)bf16_hi(wf - bf16_f(hi)); }
        {   const float wf = W_s[(32 + 8 * q + e) * HID + wcol];
            const ushort hi = bf16_hi(wf);
            Whi1[e] = (short)hi;
            Wlo1[e] = (short)bf16_hi(wf - bf16_f(hi)); }
    }
    // Pin in VGPRs (round-1 lesson: const global loads get rematerialized).
    asm volatile("" : "+v"(Whi0), "+v"(Whi1), "+v"(Wlo0), "+v"(Wlo1));

    // zero h buffers; ordered before first read by the staging barrier
    {
        ushort* p = &hlds[0][0];
        for (int i = tid; i < 2 * RPG * ROWU; i += 512) p[i] = 0;
    }

    // Swizzle for this lane's row.
    const int sx = (rr & 7) ^ ((rr >> 3) * 5);

    // Read addr regs: hi slot q and hi slot q^4 (lo at +64 ushorts = offset:128).
    const ushort* const rA0 = &hlds[0][rr * ROWU + 8 * (q ^ sx)];
    const ushort* const rA1 = &hlds[0][rr * ROWU + 8 * ((q ^ 4) ^ sx)];
    const ushort* const rB0 = &hlds[1][rr * ROWU + 8 * (q ^ sx)];
    const ushort* const rB1 = &hlds[1][rr * ROWU + 8 * ((q ^ 4) ^ sx)];

    // Write pointers: c0 = cq + 2hf -> logical slot l = c0>>3, within = c0&7.
    const int c0  = cq + 2 * hf;
    const int wl  = c0 >> 3;
    const int win_idx = rr * ROWU + 8 * (wl ^ sx) + (c0 & 7);
    unsigned* const whiA = reinterpret_cast<unsigned*>(&hlds[0][win_idx]);
    unsigned* const wloA = reinterpret_cast<unsigned*>(&hlds[0][win_idx + 64]);
    unsigned* const whiB = reinterpret_cast<unsigned*>(&hlds[1][win_idx]);
    unsigned* const wloB = reinterpret_cast<unsigned*>(&hlds[1][win_idx + 64]);

    const int nch = T >> 6;           // T multiple of 64 (8192 here)

    if (hf == 0) { MAINLOOP(0, 1) } else { MAINLOOP(2, 3) }

    // Epilogue: h final in hlds[0] (even step count). out[b] = h.W_out + b_out.
    if (ww == 0) {
        const int r  = lane >> 2;
        const int p4 = lane & 3;
        const int sxr = (r & 7) ^ ((r >> 3) * 5);
        float s = 0.f;
#pragma unroll
        for (int half = 0; half < 2; ++half) {
            const int slot = 2 * p4 + half;                 // logical slot
            const ushort* hp = &hlds[0][r * ROWU + 8 * (slot ^ sxr)];
            const ushort* lp = hp + 64;
#pragma unroll
            for (int j = 0; j < 8; ++j) {
                const float hv = bf16_f(hp[j]) + bf16_f(lp[j]);
                s = __builtin_fmaf(hv, W_out[8 * slot + j], s);
            }
        }
        s += __shfl_xor(s, 1, 64);
        s += __shfl_xor(s, 2, 64);
        if (p4 == 0) out[bA + r] = s + b_out[0];
    }
}

extern "C" void kernel_launch(void* const* d_in, const int* in_sizes, int n_in,
                              void* d_out, int out_size, void* d_ws, size_t ws_size,
                              hipStream_t stream) {
    const float* x     = (const float*)d_in[0];
    const float* W_in  = (const float*)d_in[1];
    const float* b_in  = (const float*)d_in[2];
    const float* W_s   = (const float*)d_in[3];
    const float* b_s   = (const float*)d_in[4];
    const float* W_out = (const float*)d_in[5];
    const float* b_out = (const float*)d_in[6];
    float* out = (float*)d_out;

    const int B = out_size;                 // [B,1] output
    const int T = in_sizes[0] / B;          // x is [B,T,1]

    const int blocks = B / RPG;             // 256 for B=4096
    ssm_kernel<<<blocks, 512, 0, stream>>>(
        x, W_in, b_in, W_s, b_s, W_out, b_out, out, B, T);
}

// Round 14
// 2565.031 us; speedup vs baseline: 1.5170x; 1.0057x over previous
//
#include <hip/hip_runtime.h>
#include <cstdint>
#include <cstddef>

#define HID 64
#define RPG 16          // rows per block = MFMA N-tile (swapped form)
#define ROWU 144        // ushorts per h row stripe (288B): [hi 8x16B][lo 8x16B][pad 32B]
#define XSTR 68         // floats per x row: 272 B

typedef short bf16x8 __attribute__((ext_vector_type(8)));
typedef float f32x4 __attribute__((ext_vector_type(4)));
typedef float f32x2 __attribute__((ext_vector_type(2)));

__device__ __forceinline__ f32x2 c2(float v) { f32x2 r = {v, v}; return r; }

// Packed exact-erf GELU (A&S 7.1.26, max |erf err| ~1.5e-7) on BOTH elements
// at once: v_pk_fma/mul for the polynomial, scalar v_rcp/v_exp for the trans.
__device__ __forceinline__ f32x2 fast_gelu2(f32x2 z) {
    const f32x2 u = z * 0.70710678118654752f;
    const f32x2 a = __builtin_elementwise_abs(u);
    const f32x2 d = __builtin_elementwise_fma(c2(0.3275911f), a, c2(1.0f));
    f32x2 t;
    t.x = __builtin_amdgcn_rcpf(d.x);
    t.y = __builtin_amdgcn_rcpf(d.y);
    const f32x2 s = u * 1.20112240878645f;      // sqrt(log2 e)
    f32x2 e;
    e.x = __builtin_amdgcn_exp2f(-(s.x * s.x)); // exp(-u^2)
    e.y = __builtin_amdgcn_exp2f(-(s.y * s.y));
    f32x2 p = c2(1.061405429f);
    p = __builtin_elementwise_fma(p, t, c2(-1.453152027f));
    p = __builtin_elementwise_fma(p, t, c2( 1.421413741f));
    p = __builtin_elementwise_fma(p, t, c2(-0.284496736f));
    p = __builtin_elementwise_fma(p, t, c2( 0.254829592f));
    p = p * t;
    f32x2 er = __builtin_elementwise_fma(-p, e, c2(1.0f));
    er = __builtin_elementwise_copysign(er, u);
    const f32x2 zh = z * 0.5f;
    return __builtin_elementwise_fma(zh, er, zh);
}

__device__ __forceinline__ ushort bf16_hi(float f) {
    return (ushort)(__float_as_uint(f) >> 16);
}
__device__ __forceinline__ float bf16_f(ushort u) {
    return __uint_as_float(((unsigned)u) << 16);
}

// Pack top halves of two f32 bit-patterns into one u32: {lo16=a>>16, hi16=b>>16}.
#define PKHI(b_, a_) __builtin_amdgcn_perm((b_), (a_), 0x07060302u)

// One step, swapped form: D'[c'][r] = sum_k W^T[c'][k] h[k][r].
// A = W^T (static regs), B = h from swizzled LDS stripes (4x ds_read_b128).
// Bias rides as C-in of the ac1 chain at literal elements E0,E1.
// Elements E0,E1 finished with PACKED f32 math; one u32 write per plane.
#define STEP(RA0, RA1, WHI, WLO, XB, E0, E1) { \
    const bf16x8 Hhi0 = *reinterpret_cast<const bf16x8*>(RA0); \
    const bf16x8 Hlo0 = *reinterpret_cast<const bf16x8*>((RA0) + 64); \
    const bf16x8 Hhi1 = *reinterpret_cast<const bf16x8*>(RA1); \
    const bf16x8 Hlo1 = *reinterpret_cast<const bf16x8*>((RA1) + 64); \
    const f32x2 biv = __builtin_elementwise_fma(c2(XB), winv, cbv); \
    f32x4 ci = {0.f, 0.f, 0.f, 0.f}; \
    ci[E0] = biv.x; \
    ci[E1] = biv.y; \
    const f32x4 zz = {0.f, 0.f, 0.f, 0.f}; \
    f32x4 ahh = __builtin_amdgcn_mfma_f32_16x16x32_bf16(Whi0, Hhi0, zz, 0, 0, 0); \
    f32x4 ac1 = __builtin_amdgcn_mfma_f32_16x16x32_bf16(Whi0, Hlo0, ci, 0, 0, 0); \
    f32x4 ac2 = __builtin_amdgcn_mfma_f32_16x16x32_bf16(Wlo0, Hhi0, zz, 0, 0, 0); \
    ahh = __builtin_amdgcn_mfma_f32_16x16x32_bf16(Whi1, Hhi1, ahh, 0, 0, 0); \
    ac1 = __builtin_amdgcn_mfma_f32_16x16x32_bf16(Whi1, Hlo1, ac1, 0, 0, 0); \
    ac2 = __builtin_amdgcn_mfma_f32_16x16x32_bf16(Wlo1, Hhi1, ac2, 0, 0, 0); \
    f32x2 pa, pb, pc; \
    pa.x = ahh[E0]; pa.y = ahh[E1]; \
    pb.x = ac1[E0]; pb.y = ac1[E1]; \
    pc.x = ac2[E0]; pc.y = ac2[E1]; \
    const f32x2 zv = (pa + pb) + pc; \
    const f32x2 hv = fast_gelu2(zv); \
    const unsigned hb0 = __float_as_uint(hv.x), hb1 = __float_as_uint(hv.y); \
    *(WHI) = PKHI(hb1, hb0); \
    const f32x2 htr = { __uint_as_float(hb0 & 0xffff0000u), \
                        __uint_as_float(hb1 & 0xffff0000u) }; \
    const f32x2 lv = hv - htr; \
    *(WLO) = PKHI(__float_as_uint(lv.y), __float_as_uint(lv.x)); \
    __syncthreads(); }

// Main loop specialized per element-half so all C-vector indices are literals.
#define MAINLOOP(E0, E1) { \
    f32x2 winv, cbv; \
    winv.x = W_in[cq + E0]; winv.y = W_in[cq + E1]; \
    cbv.x  = b_in[cq + E0] + b_s[cq + E0]; \
    cbv.y  = b_in[cq + E1] + b_s[cq + E1]; \
    for (int tc = 0; tc < nch; ++tc) { \
        /* Re-pin W-frags each chunk: keeps them in arch VGPRs with a dense */ \
        /* live range (VGPR_Count=32 showed they were parked in AGPRs). */ \
        asm volatile("" : "+v"(Whi0), "+v"(Whi1), "+v"(Wlo0), "+v"(Wlo1)); \
        const size_t tg = (size_t)tc * 64; \
        { \
            const int row = tid >> 5;        /* 0..15 */ \
            const int ch  = tid & 31;        /* 0..31 -> 2 floats each */ \
            const float2 xg = *reinterpret_cast<const float2*>( \
                &x[(size_t)(bA + row) * (size_t)T + tg + ch * 2]); \
            *reinterpret_cast<float2*>(&xlds[row][ch * 2]) = xg; \
        } \
        __syncthreads(); \
        _Pragma("unroll 1") \
        for (int t4 = 0; t4 < 16; ++t4) { \
            const f32x4 xq = *reinterpret_cast<const f32x4*>(&xlds[rr][t4 * 4]); \
            STEP(rA0, rA1, whiB, wloB, xq[0], E0, E1) \
            STEP(rB0, rB1, whiA, wloA, xq[1], E0, E1) \
            STEP(rA0, rA1, whiB, wloB, xq[2], E0, E1) \
            STEP(rB0, rB1, whiA, wloA, xq[3], E0, E1) \
        } \
    } }

__global__ __launch_bounds__(512, 2)
void ssm_kernel(const float* __restrict__ x,
                const float* __restrict__ W_in,
                const float* __restrict__ b_in,
                const float* __restrict__ W_s,
                const float* __restrict__ b_s,
                const float* __restrict__ W_out,
                const float* __restrict__ b_out,
                float* __restrict__ out,
                int B, int T) {
    // h state: per row one 288B stripe = [hi 8 slots][lo 8 slots][pad], XOR-swizzled
    // 16B slots (phys = s ^ (rr&7) ^ 5*(rr>>3)); ping-pong buffers.
    __shared__ ushort hlds[2][RPG * ROWU];
    __shared__ float  xlds[RPG][XSTR];      // x[row][t_local], padded

    const int tid  = threadIdx.x;
    const int ww   = tid >> 6;        // wave 0..7
    const int g    = ww & 3;          // c-tile: owns cols [16g, 16g+16)
    const int hf   = ww >> 2;         // element-half: finishes {2hf, 2hf+1}
    const int lane = tid & 63;
    const int q    = lane >> 4;
    const int rr   = lane & 15;       // lane's batch row (C col-index)
    const int bA   = blockIdx.x * RPG;
    const int cq   = 16 * g + 4 * q;  // c-quad base this lane produces

    if (bA >= B) return;

    // A-operand = W^T tile g (static): lane rr holds W^T[c'=rr][k=8q+e].
    bf16x8 Whi0, Whi1, Wlo0, Wlo1;
    const int wcol = 16 * g + rr;
#pragma unroll
    for (int e = 0; e < 8; ++e) {
        {   const float wf = W_s[(8 * q + e) * HID + wcol];
            const ushort hi = bf16_hi(wf);
            Whi0[e] = (short)hi;
            Wlo0[e] = (short)bf16_hi(wf - bf16_f(hi)); }
        {   const float wf = W_s[(32 + 8 * q + e) * HID + wcol];
            const ushort hi = bf16_hi(wf);
            Whi1[e] = (short)hi;
            Wlo1[e] = (short)bf16_hi(wf - bf16_f(hi)); }
    }
    asm volatile("" : "+v"(Whi0), "+v"(Whi1), "+v"(Wlo0), "+v"(Wlo1));

    // zero h buffers; ordered before first read by the staging barrier
    {
        ushort* p = &hlds[0][0];
        for (int i = tid; i < 2 * RPG * ROWU; i += 512) p[i] = 0;
    }

    // Swizzle for this lane's row.
    const int sx = (rr & 7) ^ ((rr >> 3) * 5);

    // Read addr regs: hi slot q and hi slot q^4 (lo at +64 ushorts = offset:128).
    const ushort* const rA0 = &hlds[0][rr * ROWU + 8 * (q ^ sx)];
    const ushort* const rA1 = &hlds[0][rr * ROWU + 8 * ((q ^ 4) ^ sx)];
    const ushort* const rB0 = &hlds[1][rr * ROWU + 8 * (q ^ sx)];
    const ushort* const rB1 = &hlds[1][rr * ROWU + 8 * ((q ^ 4) ^ sx)];

    // Write pointers: c0 = cq + 2hf -> logical slot l = c0>>3, within = c0&7.
    const int c0  = cq + 2 * hf;
    const int wl  = c0 >> 3;
    const int win_idx = rr * ROWU + 8 * (wl ^ sx) + (c0 & 7);
    unsigned* const whiA = reinterpret_cast<unsigned*>(&hlds[0][win_idx]);
    unsigned* const wloA = reinterpret_cast<unsigned*>(&hlds[0][win_idx + 64]);
    unsigned* const whiB = reinterpret_cast<unsigned*>(&hlds[1][win_idx]);
    unsigned* const wloB = reinterpret_cast<unsigned*>(&hlds[1][win_idx + 64]);

    const int nch = T >> 6;           // T multiple of 64 (8192 here)

    if (hf == 0) { MAINLOOP(0, 1) } else { MAINLOOP(2, 3) }

    // Epilogue: h final in hlds[0] (even step count). out[b] = h.W_out + b_out.
    if (ww == 0) {
        const int r  = lane >> 2;
        const int p4 = lane & 3;
        const int sxr = (r & 7) ^ ((r >> 3) * 5);
        float s = 0.f;
#pragma unroll
        for (int half = 0; half < 2; ++half) {
            const int slot = 2 * p4 + half;                 // logical slot
            const ushort* hp = &hlds[0][r * ROWU + 8 * (slot ^ sxr)];
            const ushort* lp = hp + 64;
#pragma unroll
            for (int j = 0; j < 8; ++j) {
                const float hv = bf16_f(hp[j]) + bf16_f(lp[j]);
                s = __builtin_fmaf(hv, W_out[8 * slot + j], s);
            }
        }
        s += __shfl_xor(s, 1, 64);
        s += __shfl_xor(s, 2, 64);
        if (p4 == 0) out[bA + r] = s + b_out[0];
    }
}

extern "C" void kernel_launch(void* const* d_in, const int* in_sizes, int n_in,
                              void* d_out, int out_size, void* d_ws, size_t ws_size,
                              hipStream_t stream) {
    const float* x     = (const float*)d_in[0];
    const float* W_in  = (const float*)d_in[1];
    const float* b_in  = (const float*)d_in[2];
    const float* W_s   = (const float*)d_in[3];
    const float* b_s   = (const float*)d_in[4];
    const float* W_out = (const float*)d_in[5];
    const float* b_out = (const float*)d_in[6];
    float* out = (float*)d_out;

    const int B = out_size;                 // [B,1] output
    const int T = in_sizes[0] / B;          // x is [B,T,1]

    const int blocks = B / RPG;             // 256 for B=4096
    ssm_kernel<<<blocks, 512, 0, stream>>>(
        x, W_in, b_in, W_s, b_s, W_out, b_out, out, B, T);
}